// Round 13
// baseline (167.898 us; speedup 1.0000x reference)
//
#include <hip/hip_runtime.h>
#include <stdint.h>

// Problem: out[m][n] = sum_k x[m][k] * w[n][k] + bias[n]
//   M=256, N=16384, K=4096, w = dequant(2-bit, group=16 along k)
// Round 13: quarter-size blocks for 8 barrier domains / 32 waves per CU.
//  - 256-thr blocks: 2 CONSUMER waves (32m x 64n each) + 2 PRODUCER waves
//    (each lane owns 2 groups); BM=64, BN=64, BK=64, 2-deep dbuf (16 KiB).
//  - grid (256,4) = 1024 blocks = 8 blocks/CU (128 KiB LDS, VGPR<=64 ->
//    8 waves/SIMD). Same-x blocks share q2 via same-XCD L2.
//  - per-wave work identical to the proven round-10/12 pattern: XOR-swizzled
//    B LDS, lgkm-only barrier, A reg-prefetch from coalesced workspace,
//    q2/nrm prefetch 2 tiles deep, setprio around MFMA.
// Accepted costs: dequant x4 chip-wide, q2 L2 reads x4, LDS/FLOP +20%.
#define M_DIM 256
#define N_DIM 16384
#define K_DIM 4096
#define BN 64
#define BK 64
#define NT (K_DIM / BK)   // 64 k-tiles

typedef __bf16 bf16x8 __attribute__((ext_vector_type(8)));
typedef float  f32x4  __attribute__((ext_vector_type(4)));

// fp32 -> bf16 bits, round-nearest-even (finite inputs)
__device__ __forceinline__ uint32_t f2bf(float f) {
  uint32_t u = __float_as_uint(f);
  return (u + 0x7fffu + ((u >> 16) & 1u)) >> 16;
}

// Barrier that waits ONLY on LDS ops -- global prefetches stay in flight.
#define LDS_BARRIER() \
  asm volatile("s_waitcnt lgkmcnt(0)\n\ts_barrier" ::: "memory")

// ---------------------------------------------------------------------------
// Kernel 1: x fp32 [256][4096] -> bf16 fragment-chunk order (unchanged).
// Chunk = (m-block of 16 rows) x (k-chunk of 32): 64 slots x 16B.
// Slot L holds row (L&15), k = (L>>4)*8 .. +7  (MFMA 16x16x32 A-frag order).
// ws uint4 index = (mb_glob*128 + kch)*64 + L.
// ---------------------------------------------------------------------------
__global__ __launch_bounds__(256) void cvt_x_kernel(const float* __restrict__ x,
                                                    uint4* __restrict__ ws) {
  int T = blockIdx.x * 256 + threadIdx.x;       // 0..131071
  int mb_glob = T >> 13;                        // 16 m-blocks
  int r       = T & 8191;
  int kch     = r >> 6;                         // 128 k-chunks
  int L       = r & 63;
  int row = mb_glob * 16 + (L & 15);
  int k   = kch * 32 + (L >> 4) * 8;
  const float* p = x + (size_t)row * K_DIM + k;
  float4 a = *(const float4*)p;
  float4 b = *(const float4*)(p + 4);
  uint4 o;
  o.x = f2bf(a.x) | (f2bf(a.y) << 16);
  o.y = f2bf(a.z) | (f2bf(a.w) << 16);
  o.z = f2bf(b.x) | (f2bf(b.y) << 16);
  o.w = f2bf(b.z) | (f2bf(b.w) << 16);
  ws[T] = o;
}

// ---------------------------------------------------------------------------
// Dequant 8 elems (2 packed q2 words; 4 crumbs in each low byte) of one group.
// Table entries {-n, a-n, 2a-n, 3a-n}, a = n*2/3 -- bit-identical to the
// fmaf+f2bf reference path.  v_perm_b32 picks the bf16 entry per crumb.
// ---------------------------------------------------------------------------
__device__ __forceinline__ uint4 deq8(uint32_t qx, uint32_t qy, uint32_t tlo,
                                      uint32_t thi) {
  uint32_t s0 = ((qx & 3u) | ((qx & 0xCu) << 14)) * 0x0202u + 0x01000100u;
  uint32_t s1 = (((qx >> 4) & 3u) | ((qx & 0xC0u) << 10)) * 0x0202u + 0x01000100u;
  uint32_t s2 = ((qy & 3u) | ((qy & 0xCu) << 14)) * 0x0202u + 0x01000100u;
  uint32_t s3 = (((qy >> 4) & 3u) | ((qy & 0xC0u) << 10)) * 0x0202u + 0x01000100u;
  uint4 r;
  r.x = __builtin_amdgcn_perm(thi, tlo, s0);
  r.y = __builtin_amdgcn_perm(thi, tlo, s1);
  r.z = __builtin_amdgcn_perm(thi, tlo, s2);
  r.w = __builtin_amdgcn_perm(thi, tlo, s3);
  return r;
}

// ---------------------------------------------------------------------------
// Kernel 2: grid (256,4), 256 threads, 4 waves: 2 consumers + 2 producers.
// LDS: Bb[2][512] -- tile T in buffer T&1 (8 chunks x 64 slots each).
// ---------------------------------------------------------------------------
__global__ __launch_bounds__(256) void gemm2bit_kernel(
    const uint4*    __restrict__ aws,  // A chunks (see cvt)
    const uint32_t* __restrict__ q2,   // [G][4] packed 2-bit (low byte crumbs)
    const float*    __restrict__ nrm,  // [G] group norms (f32)
    const float*    __restrict__ bias, // [N]
    float*          __restrict__ out)  // [256][16384] fp32
{
  __shared__ uint4 Bb[2][512];  // double-buffered B tile, 16 KiB

  const int tid  = threadIdx.x;
  const int lane = tid & 63;
  const int w    = tid >> 6;    // 0..3
  const int lo4  = lane & 15;
  const int qd   = lane >> 4;
  const int n0   = blockIdx.x * BN;
  const int m0   = blockIdx.y * 64;

  if (w < 2) {
    // ================== CONSUMER wave: 32m x 64n ==========================
    const int cw  = w;           // m-panel: rows m0 + cw*32 .. +31
    const int lrs = lane ^ qd;   // swizzled read lane (matches write swizzle)

    // A frag source: m-chunks mb = blockIdx.y*4 + cw*2 + {0,1}
    const uint4* pA = aws + (size_t)(blockIdx.y * 4 + cw * 2) * 8192 + lane;

    f32x4 acc[2][4];
#pragma unroll
    for (int s = 0; s < 2; ++s)
#pragma unroll
      for (int u = 0; u < 4; ++u)
        acc[s][u] = (f32x4){0.f, 0.f, 0.f, 0.f};

    uint4 afE[4], afO[4];   // [s*2+ts] for one tile, ping-pong
#pragma unroll
    for (int s = 0; s < 2; ++s)
#pragma unroll
      for (int ts = 0; ts < 2; ++ts)
        afE[s * 2 + ts] = pA[(size_t)s * 8192 + ts * 64];
    LDS_BARRIER();   // matches producer prologue (tile 0 written)

    // tile T: prefetch A(T+1), 8 ds_read B, 16 MFMA, barrier
#define CONS_BODY(T, PR, AFC, AFN)                                              \
    do {                                                                        \
      if ((T) + 1 < NT) {                                                       \
        size_t toff = (size_t)((T) + 1) * 128;                                  \
        _Pragma("unroll")                                                       \
        for (int s = 0; s < 2; ++s)                                             \
          _Pragma("unroll")                                                     \
          for (int ts = 0; ts < 2; ++ts)                                        \
            AFN[s * 2 + ts] = pA[(size_t)s * 8192 + toff + ts * 64];            \
      }                                                                         \
      __builtin_amdgcn_s_setprio(1);                                            \
      _Pragma("unroll")                                                         \
      for (int ts = 0; ts < 2; ++ts) {                                          \
        bf16x8 bfv[4];                                                          \
        _Pragma("unroll")                                                       \
        for (int u = 0; u < 4; ++u)                                             \
          bfv[u] = *(const bf16x8*)&Bb[PR][(ts * 4 + u) * 64 + lrs];            \
        _Pragma("unroll")                                                       \
        for (int s = 0; s < 2; ++s) {                                           \
          bf16x8 av = __builtin_bit_cast(bf16x8, AFC[s * 2 + ts]);              \
          _Pragma("unroll")                                                     \
          for (int u = 0; u < 4; ++u)                                           \
            acc[s][u] = __builtin_amdgcn_mfma_f32_16x16x32_bf16(av, bfv[u],     \
                                                            acc[s][u], 0, 0, 0);\
        }                                                                       \
      }                                                                         \
      __builtin_amdgcn_s_setprio(0);                                            \
      LDS_BARRIER();                                                            \
    } while (0)

    for (int t2 = 0; t2 < NT; t2 += 2) {
      CONS_BODY(t2,     0, afE, afO);
      CONS_BODY(t2 + 1, 1, afO, afE);
    }
#undef CONS_BODY

    // epilogue: C/D layout col=lane&15 (n), row=(lane>>4)*4+reg (m)
    float bv[4];
#pragma unroll
    for (int u = 0; u < 4; ++u)
      bv[u] = bias[n0 + u * 16 + lo4];
#pragma unroll
    for (int s = 0; s < 2; ++s) {
      int mrow = m0 + cw * 32 + s * 16 + qd * 4;
#pragma unroll
      for (int u = 0; u < 4; ++u) {
        int ncol = n0 + u * 16 + lo4;
        float* p = out + (size_t)mrow * N_DIM + ncol;
#pragma unroll
        for (int r = 0; r < 4; ++r)
          p[(size_t)r * N_DIM] = acc[s][u][r] + bv[u];
      }
    }
  } else {
    // ======= PRODUCER wave: 2 groups per lane (rows ra, ra+16; same kg) ====
    const int p     = w - 2;        // n-32-half 0..1
    const int kg    = lane & 3;     // k-group within BK (0..3)
    const int n_loc = lane >> 2;    // 0..15
    const int ra    = n0 + p * 32 + n_loc;        // row in 16-block nba
    const int rb    = ra + 16;                    // row in 16-block nbb
    const int nba   = p * 2;
    const int nbb   = p * 2 + 1;
    const int qd2a  = (kg & 1) * 2;
    const int qd2b  = qd2a + 1;
    const int ba    = ((kg >> 1) * 4 + nba) * 64;
    const int bb    = ((kg >> 1) * 4 + nbb) * 64;
    const int sAa = ba + qd2a * 16 + (n_loc ^ qd2a);
    const int sBa = ba + qd2b * 16 + (n_loc ^ qd2b);
    const int sAb = bb + qd2a * 16 + (n_loc ^ qd2a);
    const int sBb = bb + qd2b * 16 + (n_loc ^ qd2b);

    const uint32_t* pqa = q2 + ((size_t)ra * 256 + kg) * 4;  // +16 words/tile
    const uint32_t* pqb = q2 + ((size_t)rb * 256 + kg) * 4;
    const float*    pna = nrm + (size_t)ra * 256 + kg;       // +4/tile
    const float*    pnb = nrm + (size_t)rb * 256 + kg;

#define DEQ_GROUP(WB, Q, NV, SA, SB)                                            \
    do {                                                                        \
      float a2_ = (NV) * (2.0f / 3.0f);                                         \
      uint32_t tlo_ = f2bf(-(NV)) | (f2bf(fmaf(1.0f, a2_, -(NV))) << 16);       \
      uint32_t thi_ = f2bf(fmaf(2.0f, a2_, -(NV))) |                            \
                      (f2bf(fmaf(3.0f, a2_, -(NV))) << 16);                     \
      Bb[WB][SA] = deq8((Q).x, (Q).y, tlo_, thi_);                              \
      Bb[WB][SB] = deq8((Q).z, (Q).w, tlo_, thi_);                              \
    } while (0)

    // prologue: dequant tile 0 -> buf 0; prefetch q(1)->E, q(2)->O
    {
      uint4 t0a = *(const uint4*)pqa;  float y0a = pna[0];
      uint4 t0b = *(const uint4*)pqb;  float y0b = pnb[0];
      DEQ_GROUP(0, t0a, y0a, sAa, sBa);
      DEQ_GROUP(0, t0b, y0b, sAb, sBb);
    }
    uint4 qEa = *(const uint4*)(pqa + 16);  float nEa = pna[4];   // tile 1
    uint4 qEb = *(const uint4*)(pqb + 16);  float nEb = pnb[4];
    uint4 qOa = *(const uint4*)(pqa + 32);  float nOa = pna[8];   // tile 2
    uint4 qOb = *(const uint4*)(pqb + 32);  float nOb = pnb[8];
    LDS_BARRIER();

    // body T: write tile T+1 (q loaded at T-2) into buf PR^1; reload q(T+3)
#define PROD_BODY(T, PR, QA, NA, QB, NB)                                        \
    do {                                                                        \
      if ((T) + 1 < NT) {                                                       \
        DEQ_GROUP((PR) ^ 1, QA, NA, sAa, sBa);                                  \
        DEQ_GROUP((PR) ^ 1, QB, NB, sAb, sBb);                                  \
      }                                                                         \
      if ((T) + 3 < NT) {                                                       \
        QA = *(const uint4*)(pqa + (size_t)((T) + 3) * 16);                     \
        NA = pna[(size_t)((T) + 3) * 4];                                        \
        QB = *(const uint4*)(pqb + (size_t)((T) + 3) * 16);                     \
        NB = pnb[(size_t)((T) + 3) * 4];                                        \
      }                                                                         \
      LDS_BARRIER();                                                            \
    } while (0)

    for (int t2 = 0; t2 < NT; t2 += 2) {
      PROD_BODY(t2,     0, qEa, nEa, qEb, nEb);
      PROD_BODY(t2 + 1, 1, qOa, nOa, qOb, nOb);
    }
#undef PROD_BODY
#undef DEQ_GROUP
  }
}

// ---------------------------------------------------------------------------
extern "C" void kernel_launch(void* const* d_in, const int* in_sizes, int n_in,
                              void* d_out, int out_size, void* d_ws, size_t ws_size,
                              hipStream_t stream) {
  const float*    x    = (const float*)d_in[0];
  const uint32_t* q2   = (const uint32_t*)d_in[1];
  const float*    nm   = (const float*)d_in[2];
  const float*    bias = (const float*)d_in[3];
  float*          out  = (float*)d_out;
  uint4*          aws  = (uint4*)d_ws;   // 2 MiB: x as bf16 fragment chunks

  cvt_x_kernel<<<512, 256, 0, stream>>>(x, aws);
  gemm2bit_kernel<<<dim3(N_DIM / BN, 4), 256, 0, stream>>>(aws, q2, nm, bias, out);
}

// Round 15
// 151.639 us; speedup vs baseline: 1.1072x; 1.1072x over previous
//
#include <hip/hip_runtime.h>
#include <stdint.h>

// Problem: out[m][n] = sum_k x[m][k] * w[n][k] + bias[n]
//   M=256, N=16384, K=4096, w = dequant(2-bit, group=16 along k)
// Round 15: the 24-waves/CU experiment round 14 botched (its 16m x 32n
// consumers covered only HALF the tile -> absmax fail). Correct split:
//  - 8 CONSUMER waves = 4 m-panels x 2 K-HALVES. Wave (wm,kh) computes
//    32m x 64n over k-half kh of every BK=64 tile (4 ds_read + 8 MFMA/tile).
//    Coverage: full 128x64 per tile, A read once (kch parity disjoint),
//    B LDS amplification unchanged (8 waves x 4KB = 32KB/tile), dequant 2x.
//  - 4 PRODUCER waves: verbatim round 12.
//  - epilogue: k-half partners merge partials through the 32KB ring memory
//    (reused as scratch), kh=0 stores merged + bias.
//  - grid (256,2) x 768 thr = 2 blocks/CU x 12 waves = 24 waves/CU (was 16).
// Per-CU traffic on every pipe identical to round 12 (61us best) -- pure TLP.
// Skeleton: BM=128/BN=64/BK=64, 4-deep LDS ring, barrier per 2 tiles,
// XOR-swizzled B LDS, lgkm-only barrier, A via coalesced fragment workspace,
// q2/nrm prefetch 2 tile-pairs deep, setprio around MFMA.
#define M_DIM 256
#define N_DIM 16384
#define K_DIM 4096
#define BN 64
#define BK 64
#define NT (K_DIM / BK)   // 64 k-tiles

typedef __bf16 bf16x8 __attribute__((ext_vector_type(8)));
typedef float  f32x4  __attribute__((ext_vector_type(4)));

// fp32 -> bf16 bits, round-nearest-even (finite inputs)
__device__ __forceinline__ uint32_t f2bf(float f) {
  uint32_t u = __float_as_uint(f);
  return (u + 0x7fffu + ((u >> 16) & 1u)) >> 16;
}

// Barrier that waits ONLY on LDS ops -- global prefetches stay in flight.
#define LDS_BARRIER() \
  asm volatile("s_waitcnt lgkmcnt(0)\n\ts_barrier" ::: "memory")

// ---------------------------------------------------------------------------
// Kernel 1: x fp32 [256][4096] -> bf16 fragment-chunk order (unchanged).
// Chunk = (m-block of 16 rows) x (k-chunk of 32): 64 slots x 16B.
// Slot L holds row (L&15), k = (L>>4)*8 .. +7  (MFMA 16x16x32 A-frag order).
// ws uint4 index = (mb_glob*128 + kch)*64 + L.
// ---------------------------------------------------------------------------
__global__ __launch_bounds__(256) void cvt_x_kernel(const float* __restrict__ x,
                                                    uint4* __restrict__ ws) {
  int T = blockIdx.x * 256 + threadIdx.x;       // 0..131071
  int mb_glob = T >> 13;                        // 16 m-blocks
  int r       = T & 8191;
  int kch     = r >> 6;                         // 128 k-chunks
  int L       = r & 63;
  int row = mb_glob * 16 + (L & 15);
  int k   = kch * 32 + (L >> 4) * 8;
  const float* p = x + (size_t)row * K_DIM + k;
  float4 a = *(const float4*)p;
  float4 b = *(const float4*)(p + 4);
  uint4 o;
  o.x = f2bf(a.x) | (f2bf(a.y) << 16);
  o.y = f2bf(a.z) | (f2bf(a.w) << 16);
  o.z = f2bf(b.x) | (f2bf(b.y) << 16);
  o.w = f2bf(b.z) | (f2bf(b.w) << 16);
  ws[T] = o;
}

// ---------------------------------------------------------------------------
// Dequant 8 elems (2 packed q2 words; 4 crumbs in each low byte) of one group.
// Table entries {-n, a-n, 2a-n, 3a-n}, a = n*2/3 -- bit-identical to the
// fmaf+f2bf reference path.  v_perm_b32 picks the bf16 entry per crumb.
// ---------------------------------------------------------------------------
__device__ __forceinline__ uint4 deq8(uint32_t qx, uint32_t qy, uint32_t tlo,
                                      uint32_t thi) {
  uint32_t s0 = ((qx & 3u) | ((qx & 0xCu) << 14)) * 0x0202u + 0x01000100u;
  uint32_t s1 = (((qx >> 4) & 3u) | ((qx & 0xC0u) << 10)) * 0x0202u + 0x01000100u;
  uint32_t s2 = ((qy & 3u) | ((qy & 0xCu) << 14)) * 0x0202u + 0x01000100u;
  uint32_t s3 = (((qy >> 4) & 3u) | ((qy & 0xC0u) << 10)) * 0x0202u + 0x01000100u;
  uint4 r;
  r.x = __builtin_amdgcn_perm(thi, tlo, s0);
  r.y = __builtin_amdgcn_perm(thi, tlo, s1);
  r.z = __builtin_amdgcn_perm(thi, tlo, s2);
  r.w = __builtin_amdgcn_perm(thi, tlo, s3);
  return r;
}

// ---------------------------------------------------------------------------
// Kernel 2: grid (256,2), 768 threads, 12 waves: 8 consumers + 4 producers.
// LDS: Bb[4][512] -- tile T in buffer T&3 (8 chunks x 64 slots each);
// reused as 32KB merge scratch in the epilogue.
// ---------------------------------------------------------------------------
__global__ __launch_bounds__(768, 6) void gemm2bit_kernel(
    const uint4*    __restrict__ aws,  // A chunks (see cvt)
    const uint32_t* __restrict__ q2,   // [G][4] packed 2-bit (low byte crumbs)
    const float*    __restrict__ nrm,  // [G] group norms (f32)
    const float*    __restrict__ bias, // [N]
    float*          __restrict__ out)  // [256][16384] fp32
{
  __shared__ uint4 Bb[4][512];  // 4-deep tile ring, 32 KiB (+ epilogue scratch)

  const int tid  = threadIdx.x;
  const int lane = tid & 63;
  const int w    = tid >> 6;    // 0..11
  const int lo4  = lane & 15;
  const int qd   = lane >> 4;
  const int n0   = blockIdx.x * BN;
  const int m0   = blockIdx.y * 128;

  if (w < 8) {
    // ============ CONSUMER wave: 32m x 64n, k-half kh of each tile =========
    const int wm  = w & 3;       // m-panel: rows m0 + wm*32 .. +31
    const int kh  = w >> 2;      // k-half: ts = kh (k 32*kh .. +31 of tile)
    const int lrs = lane ^ qd;   // swizzled read lane (matches write swizzle)

    // A frag source: m-chunks mb = blockIdx.y*8 + wm*2 + s, kch = 2T + kh
    const uint4* pA = aws + (size_t)(blockIdx.y * 8 + wm * 2) * 8192 +
                      kh * 64 + lane;

    f32x4 acc[2][4];
#pragma unroll
    for (int s = 0; s < 2; ++s)
#pragma unroll
      for (int u = 0; u < 4; ++u)
        acc[s][u] = (f32x4){0.f, 0.f, 0.f, 0.f};

    uint4 afE[2], afO[2];   // [s] one k-chunk per tile, ping-pong
#pragma unroll
    for (int s = 0; s < 2; ++s) afE[s] = pA[(size_t)s * 8192];
    const uint4* pAp = pA + 128;   // next tile's chunk
    LDS_BARRIER();   // matches producer prologue (tiles 0,1 written)

    // tile: prefetch A(next), 4 ds_read B (own k-half), 8 MFMA
#define CONS_TILE(BUF, AFC, AFN, TNEXT)                                         \
    do {                                                                        \
      if ((TNEXT) < NT) {                                                       \
        _Pragma("unroll")                                                       \
        for (int s = 0; s < 2; ++s) AFN[s] = pAp[(size_t)s * 8192];             \
      }                                                                         \
      pAp += 128;                                                               \
      __builtin_amdgcn_s_setprio(1);                                            \
      bf16x8 bfv[4];                                                            \
      _Pragma("unroll")                                                         \
      for (int u = 0; u < 4; ++u)                                               \
        bfv[u] = *(const bf16x8*)&Bb[BUF][(kh * 4 + u) * 64 + lrs];             \
      _Pragma("unroll")                                                         \
      for (int s = 0; s < 2; ++s) {                                             \
        bf16x8 av = __builtin_bit_cast(bf16x8, AFC[s]);                         \
        _Pragma("unroll")                                                       \
        for (int u = 0; u < 4; ++u)                                             \
          acc[s][u] = __builtin_amdgcn_mfma_f32_16x16x32_bf16(av, bfv[u],       \
                                                          acc[s][u], 0, 0, 0);  \
      }                                                                         \
      __builtin_amdgcn_s_setprio(0);                                            \
    } while (0)

    for (int tp = 0; tp < NT; tp += 4) {
      // phase A: tiles tp, tp+1 from bufs 0,1 (producers writing 2,3)
      CONS_TILE(0, afE, afO, tp + 1);
      CONS_TILE(1, afO, afE, tp + 2);
      LDS_BARRIER();
      // phase B: tiles tp+2, tp+3 from bufs 2,3 (producers writing 0,1)
      CONS_TILE(2, afE, afO, tp + 3);
      CONS_TILE(3, afO, afE, tp + 4);
      LDS_BARRIER();
    }
#undef CONS_TILE

    // ---- epilogue: kh=1 shares partials via ring-as-scratch; kh=0 merges,
    // adds bias, stores. C/D: col=lane&15 (n), row=(lane>>4)*4+reg (m). ----
    uint4* Sc = &Bb[0][0];   // 2048 uint4 = 32 KiB; index max = 2047
    if (kh == 1) {
#pragma unroll
      for (int s = 0; s < 2; ++s)
#pragma unroll
        for (int u = 0; u < 4; ++u)
          Sc[((wm * 2 + s) * 4 + u) * 64 + lane] =
              __builtin_bit_cast(uint4, acc[s][u]);
    }
    LDS_BARRIER();
    if (kh == 0) {
      float bv[4];
#pragma unroll
      for (int u = 0; u < 4; ++u)
        bv[u] = bias[n0 + u * 16 + lo4];
#pragma unroll
      for (int s = 0; s < 2; ++s) {
        int mrow = m0 + wm * 32 + s * 16 + qd * 4;
#pragma unroll
        for (int u = 0; u < 4; ++u) {
          f32x4 o = acc[s][u] + __builtin_bit_cast(
                        f32x4, Sc[((wm * 2 + s) * 4 + u) * 64 + lane]);
          int ncol = n0 + u * 16 + lo4;
          float* p = out + (size_t)mrow * N_DIM + ncol;
#pragma unroll
          for (int r = 0; r < 4; ++r)
            p[(size_t)r * N_DIM] = o[r] + bv[u];
        }
      }
    }
  } else {
    // ================== PRODUCER wave: 16n x 4 k-groups (as round 12) =====
    const int pw    = w - 8;        // n-16-block 0..3
    const int kg    = lane & 3;     // k-group within BK (0..3)
    const int n_loc = lane >> 2;    // 0..15
    const int grow  = n0 + pw * 16 + n_loc;
    const int qd2a  = (kg & 1) * 2;
    const int qd2b  = qd2a + 1;
    const int bsA = ((kg >> 1) * 4 + pw) * 64 + qd2a * 16 + (n_loc ^ qd2a);
    const int bsB = ((kg >> 1) * 4 + pw) * 64 + qd2b * 16 + (n_loc ^ qd2b);

    const uint32_t* pq = q2 + ((size_t)grow * 256 + kg) * 4;  // +16 words/tile
    const float*    pn = nrm + (size_t)grow * 256 + kg;       // +4/tile

#define DEQ_TILE(WB, Q, NV)                                                     \
    do {                                                                        \
      float a2_ = (NV) * (2.0f / 3.0f);                                         \
      uint32_t tlo_ = f2bf(-(NV)) | (f2bf(fmaf(1.0f, a2_, -(NV))) << 16);       \
      uint32_t thi_ = f2bf(fmaf(2.0f, a2_, -(NV))) |                            \
                      (f2bf(fmaf(3.0f, a2_, -(NV))) << 16);                     \
      Bb[WB][bsA] = deq8((Q).x, (Q).y, tlo_, thi_);                             \
      Bb[WB][bsB] = deq8((Q).z, (Q).w, tlo_, thi_);                             \
    } while (0)

    // prologue: deq tiles 0,1 -> bufs 0,1; hold (2,3)->E, (4,5)->O in flight
    {
      uint4 t0 = *(const uint4*)pq;         float y0 = pn[0];
      uint4 t1 = *(const uint4*)(pq + 16);  float y1 = pn[4];
      DEQ_TILE(0, t0, y0);
      DEQ_TILE(1, t1, y1);
    }
    uint4 qE0 = *(const uint4*)(pq + 32);  float nE0 = pn[8];    // tile 2
    uint4 qE1 = *(const uint4*)(pq + 48);  float nE1 = pn[12];   // tile 3
    uint4 qO0 = *(const uint4*)(pq + 64);  float nO0 = pn[16];   // tile 4
    uint4 qO1 = *(const uint4*)(pq + 80);  float nO1 = pn[20];   // tile 5
    const uint32_t* pql = pq + 96;   // tile 6; +32 words per phase
    const float*    pnl = pn + 24;
    LDS_BARRIER();

    for (int tp = 0; tp < NT; tp += 4) {
      // phase A: write tiles tp+2,tp+3 -> bufs 2,3; reload E = tp+6,tp+7
      if (tp + 2 < NT) {
        DEQ_TILE(2, qE0, nE0);
        DEQ_TILE(3, qE1, nE1);
      }
      if (tp + 6 < NT) {
        qE0 = *(const uint4*)pql;        nE0 = pnl[0];
        qE1 = *(const uint4*)(pql + 16); nE1 = pnl[4];
      }
      pql += 32; pnl += 8;
      LDS_BARRIER();
      // phase B: write tiles tp+4,tp+5 -> bufs 0,1; reload O = tp+8,tp+9
      if (tp + 4 < NT) {
        DEQ_TILE(0, qO0, nO0);
        DEQ_TILE(1, qO1, nO1);
      }
      if (tp + 8 < NT) {
        qO0 = *(const uint4*)pql;        nO0 = pnl[0];
        qO1 = *(const uint4*)(pql + 16); nO1 = pnl[4];
      }
      pql += 32; pnl += 8;
      LDS_BARRIER();
    }
#undef DEQ_TILE
    // epilogue: match the consumers' merge barrier
    LDS_BARRIER();
  }
}

// ---------------------------------------------------------------------------
extern "C" void kernel_launch(void* const* d_in, const int* in_sizes, int n_in,
                              void* d_out, int out_size, void* d_ws, size_t ws_size,
                              hipStream_t stream) {
  const float*    x    = (const float*)d_in[0];
  const uint32_t* q2   = (const uint32_t*)d_in[1];
  const float*    nm   = (const float*)d_in[2];
  const float*    bias = (const float*)d_in[3];
  float*          out  = (float*)d_out;
  uint4*          aws  = (uint4*)d_ws;   // 2 MiB: x as bf16 fragment chunks

  cvt_x_kernel<<<512, 256, 0, stream>>>(x, aws);
  gemm2bit_kernel<<<dim3(N_DIM / BN, 2), 768, 0, stream>>>(aws, q2, nm, bias, out);
}